// Round 5
// baseline (450.568 us; speedup 1.0000x reference)
//
#include <hip/hip_runtime.h>
#include <cstddef>

// B=4, L=1024 -> ROWS=4096; m=64; Dc=256; Dq=inner=512; H=8; DH=64.
// Pipeline (exact in real arithmetic, bf16 inputs to MFMA):
//   Wqk[e,hc] = 0.125 * sum_d Wq[e,hd] Wk[c,hd]   (prep GEMM, fp32-staged, in k_prep)
//   Wvo[o,hc] = sum_d Wo[hd,o] Wv[c,hd]           (prep GEMM, fp32-staged, in k_prep)
//   Qk  = x @ Wqk          (K=512 GEMM, global_load_lds staging)
//   scores = MFMA(ctx,Qk); softmax fp32; CA = MFMA(ctx^T, attn)   (fused per-row)
//   out = CA @ Wvo^T + bo  (K=2048 GEMM, global_load_lds staging)
// Big GEMMs use m97-style staging: linear LDS + global_load_lds(16B) (no VGPR
// round-trip; read conflicts at stride-128B cost less than staging VALU — m97/m98).
// XCD-bijective block swizzle keeps all n-blocks of an m-panel on one XCD.

typedef __attribute__((ext_vector_type(8))) short short8;   // 8 bf16 fragment (4 VGPRs)
typedef __attribute__((ext_vector_type(4))) float float4v;

__device__ __forceinline__ short f2bf(float f) {   // fp32 -> bf16, round-nearest-even
  unsigned u = __float_as_uint(f);
  return (short)((u + 0x7fffu + ((u >> 16) & 1u)) >> 16);
}

#define GLDS16(g, l) __builtin_amdgcn_global_load_lds(                         \
    (const __attribute__((address_space(1))) unsigned int*)(g),                \
    (__attribute__((address_space(3))) unsigned int*)(l), 16, 0, 0)

// fp32-staged 128x64 GEMM tile, K=64 single step, padded LDS (stride 72).
// aTrans: A[row][k] = Af[k_global][m0+row] (transposed gather, for Wo).
// storeMode: 1 = bf16 straight, 2 = bf16 transposed (C[col*ldc + row]).
__device__ __forceinline__ void mm_body_f32(const float* __restrict__ Af,
                                            const float* __restrict__ Bf,
                                            void* __restrict__ C,
                                            int ldc, int aTrans, int hb,
                                            float scale, int storeMode,
                                            int bn, int bm,
                                            short* __restrict__ As,
                                            short* __restrict__ Bs) {
  int t = threadIdx.x;
  int n0 = bn * 64, m0 = bm * 128;
  int w = t >> 6, l = t & 63;
  int wm = w & 1, wn = w >> 1;
  int li = l & 15, kq = l >> 4;
#pragma unroll
  for (int p = 0; p < 4; ++p) {          // stage A: 128 rows x 64 k
    int i = p * 256 + t, row = i >> 3, kq8 = i & 7;
    float v[8];
    if (aTrans) {
#pragma unroll
      for (int j = 0; j < 8; ++j)
        v[j] = Af[(size_t)(hb * 64 + kq8 * 8 + j) * 512 + m0 + row];
    } else {
      float4 a0 = *(const float4*)(Af + (size_t)(m0 + row) * 512 + hb * 64 + kq8 * 8);
      float4 a1 = *(const float4*)(Af + (size_t)(m0 + row) * 512 + hb * 64 + kq8 * 8 + 4);
      v[0] = a0.x; v[1] = a0.y; v[2] = a0.z; v[3] = a0.w;
      v[4] = a1.x; v[5] = a1.y; v[6] = a1.z; v[7] = a1.w;
    }
    short s8[8];
#pragma unroll
    for (int j = 0; j < 8; ++j) s8[j] = f2bf(v[j]);
    *(uint4*)&As[row * 72 + kq8 * 8] = *(uint4*)s8;
  }
#pragma unroll
  for (int p = 0; p < 2; ++p) {          // stage B: 64 rows x 64 k
    int i = p * 256 + t, row = i >> 3, kq8 = i & 7;
    float4 b0 = *(const float4*)(Bf + (size_t)(n0 % 256 + row) * 512 + hb * 64 + kq8 * 8);
    float4 b1 = *(const float4*)(Bf + (size_t)(n0 % 256 + row) * 512 + hb * 64 + kq8 * 8 + 4);
    short s8[8];
    s8[0] = f2bf(b0.x); s8[1] = f2bf(b0.y); s8[2] = f2bf(b0.z); s8[3] = f2bf(b0.w);
    s8[4] = f2bf(b1.x); s8[5] = f2bf(b1.y); s8[6] = f2bf(b1.z); s8[7] = f2bf(b1.w);
    *(uint4*)&Bs[row * 72 + kq8 * 8] = *(uint4*)s8;
  }
  __syncthreads();
  float4v acc[4][2];
#pragma unroll
  for (int i = 0; i < 4; ++i)
#pragma unroll
    for (int j = 0; j < 2; ++j) acc[i][j] = (float4v){0.f, 0.f, 0.f, 0.f};
#pragma unroll
  for (int kk = 0; kk < 2; ++kk) {
    short8 af[4], bfr[2];
#pragma unroll
    for (int i = 0; i < 4; ++i)
      af[i]  = *(const short8*)&As[(wm * 64 + i * 16 + li) * 72 + kk * 32 + kq * 8];
#pragma unroll
    for (int i = 0; i < 2; ++i)
      bfr[i] = *(const short8*)&Bs[(wn * 32 + i * 16 + li) * 72 + kk * 32 + kq * 8];
#pragma unroll
    for (int mi = 0; mi < 4; ++mi)
#pragma unroll
      for (int ni = 0; ni < 2; ++ni)
        acc[mi][ni] = __builtin_amdgcn_mfma_f32_16x16x32_bf16(af[mi], bfr[ni], acc[mi][ni], 0, 0, 0);
  }
#pragma unroll
  for (int ni = 0; ni < 2; ++ni) {
    int col = n0 + wn * 32 + ni * 16 + li;
    if (storeMode == 2) {
      int row0 = m0 + wm * 64 + kq * 4;
#pragma unroll
      for (int mi = 0; mi < 4; ++mi) {
        short4 o;
        o.x = f2bf(acc[mi][ni][0] * scale);
        o.y = f2bf(acc[mi][ni][1] * scale);
        o.z = f2bf(acc[mi][ni][2] * scale);
        o.w = f2bf(acc[mi][ni][3] * scale);
        *(short4*)&((short*)C)[(size_t)col * ldc + row0 + mi * 16] = o;
      }
    } else {
#pragma unroll
      for (int mi = 0; mi < 4; ++mi)
#pragma unroll
        for (int r = 0; r < 4; ++r) {
          int row = m0 + wm * 64 + mi * 16 + kq * 4 + r;
          ((short*)C)[(size_t)row * ldc + col] = f2bf(acc[mi][ni][r] * scale);
        }
    }
  }
}

// Merged prep: x bf16 convert (blocks 0..2047) + the two weight GEMMs
// (blocks 2048..2303) staged directly from fp32 — no bf16 weight round-trips.
__global__ __launch_bounds__(256) void k_prep(const float* __restrict__ x,
                                              const float* __restrict__ Wq,
                                              const float* __restrict__ Wk,
                                              const float* __restrict__ Wv,
                                              const float* __restrict__ Wo,
                                              short* __restrict__ xb,
                                              short* __restrict__ WvoTb,
                                              short* __restrict__ WqkTb) {
  __shared__ __align__(16) short As[128 * 72];
  __shared__ __align__(16) short Bs[64 * 72];
  int b = blockIdx.x, t = threadIdx.x;
  if (b < 2048) {            // x convert, 4 elems/thread (2048*1024 = 2097152 exact)
    size_t i4 = ((size_t)b * 256 + t) * 4;
    float4 v = *(const float4*)(x + i4);
    short4 o; o.x = f2bf(v.x); o.y = f2bf(v.y); o.z = f2bf(v.z); o.w = f2bf(v.w);
    *(short4*)(xb + i4) = o;
    return;
  }
  // weight GEMMs: f in [0,256); xcd<4 -> job0 (Wvo), else job1 (Wqk)
  int f = b - 2048;
  int xcd = f & 7, bn = f >> 3;          // bn 0..31, n0 = bn*64, hb = n0>>8
  int hb = (bn * 64) >> 8;
  if (xcd < 4)   // WvoT[o, h*256+c] = sum_d Wo[hd,o] Wv[c,hd]  (A = Wo transposed)
    mm_body_f32(Wo, Wv, WvoTb, 2048, 1, hb, 1.0f, 1, bn, xcd, As, Bs);
  else           // WqkT[h*256+c, e] = 0.125 * sum_d Wq[e,hd] Wk[c,hd]  (transposed store)
    mm_body_f32(Wq, Wk, WqkTb, 512, 0, hb, 0.125f, 2, bn, xcd - 4, As, Bs);
}

// bf16 MFMA GEMM with global_load_lds staging (m97 structure): linear LDS
// [row][64] (stride 128 B), 16 B DMA per lane, lane-linear LDS dest.
// 128xBN block tile, 4 waves (2x2), wave tile 64x(BN/2), BK=64.
template<int BN>
__device__ __forceinline__ void mm_body_dma(const short* __restrict__ A,
                                            const short* __restrict__ Bt,
                                            const float* __restrict__ bias,
                                            void* __restrict__ C,
                                            int lda, int ldb, int ldc, int K,
                                            float scale, int storeBF16,
                                            int bn, int bm,
                                            short* __restrict__ As,
                                            short* __restrict__ Bs) {
  int t = threadIdx.x;
  int n0 = bn * BN, m0 = bm * 128;
  const short* aBase = A + (size_t)m0 * lda;
  const short* bBase = Bt + (size_t)n0 * ldb;
  int w = t >> 6, l = t & 63;
  int wm = w & 1, wn = w >> 1;
  int li = l & 15, kq = l >> 4;
  constexpr int NI = BN / 32;
  float4v acc[4][NI];
#pragma unroll
  for (int i = 0; i < 4; ++i)
#pragma unroll
    for (int j = 0; j < NI; ++j) acc[i][j] = (float4v){0.f, 0.f, 0.f, 0.f};

  for (int k0 = 0; k0 < K; k0 += 64) {
    __syncthreads();                     // prev compute done -> LDS reusable
#pragma unroll
    for (int p = 0; p < 4; ++p) {        // A: 128 rows x 8 slots of 16 B
      int i = p * 256 + t, row = i >> 3, sl = i & 7;
      GLDS16(aBase + (size_t)row * lda + k0 + sl * 8, &As[i * 8]);
    }
#pragma unroll
    for (int p = 0; p < BN / 32; ++p) {  // B: BN rows x 8 slots
      int i = p * 256 + t, row = i >> 3, sl = i & 7;
      GLDS16(bBase + (size_t)row * ldb + k0 + sl * 8, &Bs[i * 8]);
    }
    __syncthreads();                     // compiler drains vmcnt before barrier
#pragma unroll
    for (int kk = 0; kk < 2; ++kk) {
      short8 af[4], bfr[NI];
#pragma unroll
      for (int i = 0; i < 4; ++i)
        af[i]  = *(const short8*)&As[(wm * 64 + i * 16 + li) * 64 + kk * 32 + kq * 8];
#pragma unroll
      for (int i = 0; i < NI; ++i)
        bfr[i] = *(const short8*)&Bs[(wn * (BN / 2) + i * 16 + li) * 64 + kk * 32 + kq * 8];
#pragma unroll
      for (int mi = 0; mi < 4; ++mi)
#pragma unroll
        for (int ni = 0; ni < NI; ++ni)
          acc[mi][ni] = __builtin_amdgcn_mfma_f32_16x16x32_bf16(af[mi], bfr[ni], acc[mi][ni], 0, 0, 0);
    }
  }
#pragma unroll
  for (int ni = 0; ni < NI; ++ni) {
    int col = n0 + wn * (BN / 2) + ni * 16 + li;
    float bv = bias ? bias[col] : 0.f;
#pragma unroll
    for (int mi = 0; mi < 4; ++mi)
#pragma unroll
      for (int r = 0; r < 4; ++r) {
        int row = m0 + wm * 64 + mi * 16 + kq * 4 + r;
        float v = fmaf(acc[mi][ni][r], scale, bv);
        if (storeBF16) ((short*)C)[(size_t)row * ldc + col] = f2bf(v);
        else           ((float*)C)[(size_t)row * ldc + col] = v;
      }
  }
}

// GEMM wrapper with XCD-bijective swizzle (requires gridDim.y % 8 == 0):
// flat f = by*gx+bx; xcd = f&7; j = f>>3; bn = j%gx; bm = (j/gx)*8 + xcd.
template<int BN>
__global__ __launch_bounds__(256) void k_mm(const short* __restrict__ A,
                                            const short* __restrict__ Bt,
                                            const float* __restrict__ bias,
                                            void* __restrict__ C,
                                            int lda, int ldb, int ldc, int K,
                                            float scale, int storeBF16) {
  __shared__ __align__(16) short As[128 * 64];
  __shared__ __align__(16) short Bs[BN * 64];
  int gx = gridDim.x, gy = gridDim.y;
  int bn = blockIdx.x, bm = blockIdx.y;
  if ((gy & 7) == 0) {
    int f = blockIdx.y * gx + blockIdx.x;
    int xcd = f & 7, j = f >> 3;
    bn = j % gx;
    bm = (j / gx) * 8 + xcd;
  }
  mm_body_dma<BN>(A, Bt, bias, C, lda, ldb, ldc, K, scale, storeBF16, bn, bm, As, Bs);
}

// Fused per-row attention, MFMA-based. 1 block / (b,l) row. LDS 39.9 KB -> 4 blocks/CU.
// Phase A: stage ctx row bf16 -> mc[m][c] (64x264), Qk B-frags global->regs.
// Phase B: scores S[m,h] = MFMA(ctx, Qk)  (K=256, 8 steps; wave w owns m-tile w).
// Phase C: softmax fp32 (exact); attn -> bf16.
// Phase D: rebuild same LDS as cm[c][m] (256x72) via in-wave shfl transpose.
// Phase E: CA[c,h] = MFMA(ctx^T, attn)  (K=64, 2 steps; wave w owns 64 c's).
// MFMA cols 8..15 are discarded (8 real heads) -> B-operands read row li&7.
__global__ __launch_bounds__(256, 4) void k_attn(const float* __restrict__ ctx,
                                                 const short* __restrict__ Qkb,
                                                 const float* __restrict__ bias,
                                                 const int* __restrict__ mask,
                                                 short* __restrict__ CA) {
  __shared__ __align__(16) short uni[256 * 72];          // mc[64][264] -> cm[256][72]
  __shared__ __align__(16) float S[64][9];               // scores [m][h(8)] fp32
  __shared__ __align__(16) short attn_b[8][72];          // attn bf16 [h][m]
  __shared__ float bs[64];
  __shared__ int   msk[64];

  int t = threadIdx.x;
  int r = blockIdx.x;
  int l = t & 63, w = t >> 6;
  int li = l & 15, kq = l >> 4;

  const float* ctxr = ctx + (size_t)r * 16384;
  const short* qrow = Qkb + (size_t)r * 2048;

  // Qk B-fragments straight from global (h = lane n-index, dup for li>=8)
  int hq = l & 7;
  short8 qf[8];
#pragma unroll
  for (int ks = 0; ks < 8; ++ks)
    qf[ks] = *(const short8*)(qrow + hq * 256 + ks * 32 + kq * 8);

  if (t < 64) { bs[t] = bias[(size_t)r * 64 + t]; msk[t] = mask[(size_t)r * 64 + t]; }

  short (*mc)[264] = (short (*)[264])uni;
  short (*cm)[72]  = (short (*)[72])uni;

  // Phase A: wave w stages m rows [16w, 16w+16); lanes cover c (coalesced 1 KB/row)
  short4 sv[16];
#pragma unroll
  for (int i = 0; i < 16; ++i) {
    int m = w * 16 + i;
    float4 v = *(const float4*)(ctxr + m * 256 + l * 4);
    short4 b4; b4.x = f2bf(v.x); b4.y = f2bf(v.y); b4.z = f2bf(v.z); b4.w = f2bf(v.w);
    sv[i] = b4;
    *(short4*)&mc[m][l * 4] = b4;
  }
  __syncthreads();

  // Phase B: scores. A=ctx rows (m), B=Qk rows (h). D: col=li=h, row=kq*4+rg=m-in-16
  float4v sacc = (float4v){0.f, 0.f, 0.f, 0.f};
#pragma unroll
  for (int ks = 0; ks < 8; ++ks) {
    short8 af = *(const short8*)&mc[w * 16 + li][ks * 32 + kq * 8];
    sacc = __builtin_amdgcn_mfma_f32_16x16x32_bf16(af, qf[ks], sacc, 0, 0, 0);
  }
  if (li < 8) {
#pragma unroll
    for (int rg = 0; rg < 4; ++rg) S[w * 16 + kq * 4 + rg][li] = sacc[rg];
  }
  __syncthreads();   // also: all waves done reading mc -> region reusable

  // Phase C: softmax (fp32, exact). thread = (m_=t&63, heads h0 & h0+4)
  int m_ = t & 63, h0 = t >> 6;
  bool valid = msk[m_] != 0;
  float b = bs[m_];
  float s0 = valid ? S[m_][h0] + b : -INFINITY;
  float s1 = valid ? S[m_][h0 + 4] + b : -INFINITY;
  float mx0 = s0, mx1 = s1;
#pragma unroll
  for (int o = 32; o > 0; o >>= 1) {
    mx0 = fmaxf(mx0, __shfl_xor(mx0, o, 64));
    mx1 = fmaxf(mx1, __shfl_xor(mx1, o, 64));
  }
  float e0 = __expf(s0 - mx0), e1 = __expf(s1 - mx1);
  float sm0 = e0, sm1 = e1;
#pragma unroll
  for (int o = 32; o > 0; o >>= 1) {
    sm0 += __shfl_xor(sm0, o, 64);
    sm1 += __shfl_xor(sm1, o, 64);
  }
  attn_b[h0][m_]     = f2bf(e0 / sm0);
  attn_b[h0 + 4][m_] = f2bf(e1 / sm1);

  // Phase D: cm[c][m] from registers via in-wave transpose.
#pragma unroll
  for (int p = 0; p < 4; ++p) {
    int c  = l + p * 64;
    int sl = (l >> 2) + p * 16;
#pragma unroll
    for (int k = 0; k < 4; ++k) {
      int wd[4];
#pragma unroll
      for (int j = 0; j < 4; ++j) {
        int2 two = *(int2*)&sv[4 * k + j];
        int wx = __shfl(two.x, sl, 64);
        int wy = __shfl(two.y, sl, 64);
        wd[j] = (l & 2) ? wy : wx;
      }
      short4 o;
      o.x = (l & 1) ? (short)(wd[0] >> 16) : (short)wd[0];
      o.y = (l & 1) ? (short)(wd[1] >> 16) : (short)wd[1];
      o.z = (l & 1) ? (short)(wd[2] >> 16) : (short)wd[2];
      o.w = (l & 1) ? (short)(wd[3] >> 16) : (short)wd[3];
      *(short4*)&cm[c][w * 16 + k * 4] = o;
    }
  }
  __syncthreads();

  // Phase E: CA. A=ctx^T rows (c), B=attn rows (h), K=m. D: col=li=h, row=c-in-16
  short8 bfr[2];
#pragma unroll
  for (int ks = 0; ks < 2; ++ks)
    bfr[ks] = *(const short8*)&attn_b[li & 7][ks * 32 + kq * 8];
  float4v ca[4];
#pragma unroll
  for (int mi = 0; mi < 4; ++mi) ca[mi] = (float4v){0.f, 0.f, 0.f, 0.f};
#pragma unroll
  for (int mi = 0; mi < 4; ++mi)
#pragma unroll
    for (int ks = 0; ks < 2; ++ks) {
      short8 af = *(const short8*)&cm[w * 64 + mi * 16 + li][ks * 32 + kq * 8];
      ca[mi] = __builtin_amdgcn_mfma_f32_16x16x32_bf16(af, bfr[ks], ca[mi], 0, 0, 0);
    }
  short* car = CA + (size_t)r * 2048;
  if (li < 8) {
#pragma unroll
    for (int mi = 0; mi < 4; ++mi)
#pragma unroll
      for (int rg = 0; rg < 4; ++rg)
        car[li * 256 + w * 64 + mi * 16 + kq * 4 + rg] = f2bf(ca[mi][rg]);
  }
}

extern "C" void kernel_launch(void* const* d_in, const int* in_sizes, int n_in,
                              void* d_out, int out_size, void* d_ws, size_t ws_size,
                              hipStream_t stream) {
  const float* x    = (const float*)d_in[0];
  const float* ctx  = (const float*)d_in[1];
  const int*   mask = (const int*)d_in[2];
  const float* bias = (const float*)d_in[3];
  const float* Wq   = (const float*)d_in[4];
  const float* Wk   = (const float*)d_in[5];
  const float* Wv   = (const float*)d_in[6];
  const float* Wo   = (const float*)d_in[7];
  const float* bo   = (const float*)d_in[8];
  float* out = (float*)d_out;

  char* ws = (char*)d_ws;
  short* xb    = (short*)(ws);                   // 4 MB   [4096x512]
  short* Qkb   = (short*)(ws + (4u << 20));      // 16 MB  [4096x2048] bf16
  short* CAb   = (short*)(ws + (20u << 20));     // 16 MB  [4096x2048]
  short* WvoTb = (short*)(ws + (36u << 20));     // 2 MB   [512x2048]: [o][h*256+c]
  short* WqkTb = (short*)(ws + (38u << 20));     // 2 MB   [2048x512]: [h*256+c][e]

  // prep: x convert + both weight GEMMs (fp32-staged)
  k_prep<<<dim3(2304), dim3(256), 0, stream>>>(x, Wq, Wk, Wv, Wo, xb, WvoTb, WqkTb);
  // Qkb[r, hc] = sum_e xb[r,e] WqkT[hc,e]   (M=4096, N=2048, K=512)
  k_mm<128><<<dim3(16, 32), dim3(256), 0, stream>>>(xb, WqkTb, (const float*)nullptr, Qkb,
                                                    512, 512, 2048, 512, 1.0f, 1);
  // attention (MFMA)
  k_attn<<<dim3(4096), dim3(256), 0, stream>>>(ctx, Qkb, bias, mask, CAb);
  // final: out = CAb @ WvoT^T + bo   (M=4096, N=512, K=2048; 256 blocks)
  k_mm<64><<<dim3(8, 32), dim3(256), 0, stream>>>(CAb, WvoTb, bo, out,
                                                  2048, 2048, 512, 2048, 1.0f, 0);
}